// Round 2
// baseline (233.862 us; speedup 1.0000x reference)
//
#include <hip/hip_runtime.h>

// Sepconv: out[b,c,y,x] = sum_{i,j} In[b,c,y*F+i,x*F+j] * V[b,i,y,x] * H[b,j,y,x]
// B=8, C=3, F=5, HO=WO=256. fp32. Memory-bound: ~184 MB ideal traffic -> ~29 us floor.
//
// R2 structure: one block per (b,c,y) output row. The 5x5 patches for a full
// row live in 5 CONSECUTIVE input rows = 6400 contiguous floats (25.6 KB).
// Stage them to LDS with coalesced float4 loads; compute from LDS.
// LDS read bank = (5x+j)%32 -> 2-way aliasing only (free on gfx950, m136).

#define Bsz 8
#define Csz 3
#define Fsz 5
#define HOsz 256
#define WOsz 256

__global__ __launch_bounds__(256) void sepconv_kernel(
    const float* __restrict__ in,   // [B,C,HO*F,WO*F]
    const float* __restrict__ V,    // [B,F,HO,WO]
    const float* __restrict__ Hh,   // [B,F,HO,WO]
    float* __restrict__ out)        // [B,C,HO,WO]
{
    constexpr int W     = WOsz * Fsz;   // 1280 floats per input row
    constexpr int PLANE = HOsz * WOsz;  // 65536
    constexpr int NF4   = (Fsz * W) / 4; // 1600 float4s to stage

    __shared__ float smem[Fsz * W];     // 25.6 KB

    const int y  = blockIdx.x & (HOsz - 1);
    const int bc = blockIdx.x >> 8;     // b*C + c, 0..23
    const int b  = bc / Csz;
    const int x  = threadIdx.x;

    // ---- Stage 5 consecutive input rows (contiguous 25.6 KB) via float4 ----
    const float4* src = (const float4*)(in + (size_t)(bc * (HOsz * Fsz) + y * Fsz) * W);
    float4* dst = (float4*)smem;
#pragma unroll
    for (int k = threadIdx.x; k < NF4; k += 256)
        dst[k] = src[k];

    // ---- Weights: stride-1 coalesced across lanes ----
    const float* vp = V  + (size_t)b * Fsz * PLANE + y * WOsz + x;
    const float* hp = Hh + (size_t)b * Fsz * PLANE + y * WOsz + x;
    float v[Fsz], h[Fsz];
#pragma unroll
    for (int i = 0; i < Fsz; ++i) {
        v[i] = vp[(size_t)i * PLANE];
        h[i] = hp[(size_t)i * PLANE];
    }

    __syncthreads();

    // ---- Compute from LDS ----
    const float* base = smem + x * Fsz;
    float acc = 0.f;
#pragma unroll
    for (int i = 0; i < Fsz; ++i) {
        const float* row = base + i * W;
        float rs = 0.f;
#pragma unroll
        for (int j = 0; j < Fsz; ++j)
            rs = fmaf(row[j], h[j], rs);
        acc = fmaf(rs, v[i], acc);
    }

    out[(size_t)blockIdx.x * WOsz + x] = acc;
}

extern "C" void kernel_launch(void* const* d_in, const int* in_sizes, int n_in,
                              void* d_out, int out_size, void* d_ws, size_t ws_size,
                              hipStream_t stream) {
    const float* in = (const float*)d_in[0];
    const float* V  = (const float*)d_in[1];
    const float* Hh = (const float*)d_in[2];
    float* out = (float*)d_out;

    const int grid = Bsz * Csz * HOsz;  // 6144 blocks, one per (b,c,y)
    sepconv_kernel<<<grid, 256, 0, stream>>>(in, V, Hh, out);
}